// Round 16
// baseline (53.573 us; speedup 1.0000x reference)
//
#include <hip/hip_runtime.h>
#include <math.h>

#define M_WAVE 32
#define NLEN 8192
#define FFT_N 16384
#define NPAIR 528   // rec entries: 32 autos (rec[0..31]) + 496 cross (rec[32..527])

#define TWOPI_F 6.28318530717958647692f

__device__ __forceinline__ float2 cadd(float2 a, float2 b){return make_float2(a.x+b.x, a.y+b.y);}
__device__ __forceinline__ float2 csub(float2 a, float2 b){return make_float2(a.x-b.x, a.y-b.y);}
__device__ __forceinline__ float2 cmul(float2 a, float2 b){return make_float2(a.x*b.x-a.y*b.y, a.x*b.y+a.y*b.x);}
__device__ __forceinline__ float2 mul_i (float2 a){return make_float2(-a.y,  a.x);}
__device__ __forceinline__ float2 mul_mi(float2 a){return make_float2( a.y, -a.x);}

// bf16x2 pack/unpack: one complex float2 <-> one u32 (re=low16, im=high16)
__device__ __forceinline__ unsigned pkc(float2 v){
    unsigned r;
    asm("v_cvt_pk_bf16_f32 %0, %1, %2" : "=v"(r) : "v"(v.x), "v"(v.y));
    return r;
}
__device__ __forceinline__ float2 upkc(unsigned u){
    return make_float2(__uint_as_float(u << 16), __uint_as_float(u & 0xFFFF0000u));
}

__device__ __forceinline__ float2 dpp_xor1(float2 v){
    float2 r;
    r.x = __int_as_float(__builtin_amdgcn_mov_dpp(__float_as_int(v.x), 0xB1, 0xF, 0xF, true));
    r.y = __int_as_float(__builtin_amdgcn_mov_dpp(__float_as_int(v.y), 0xB1, 0xF, 0xF, true));
    return r;
}
__device__ __forceinline__ float2 dpp_xor2(float2 v){
    float2 r;
    r.x = __int_as_float(__builtin_amdgcn_mov_dpp(__float_as_int(v.x), 0x4E, 0xF, 0xF, true));
    r.y = __int_as_float(__builtin_amdgcn_mov_dpp(__float_as_int(v.y), 0x4E, 0xF, 0xF, true));
    return r;
}

__device__ __forceinline__ float waveReduceMax(float v) {
    #pragma unroll
    for (int off = 32; off > 0; off >>= 1) v = fmaxf(v, __shfl_down(v, off, 64));
    return v;
}
__device__ __forceinline__ float waveReduceSum(float v) {
    #pragma unroll
    for (int off = 32; off > 0; off >>= 1) v += __shfl_down(v, off, 64);
    return v;
}

// ---------- classic dft16 (natural order) ----------
template<int SGN>
__device__ __forceinline__ void dft16_tail(float2 w[16], float2 v[16]){
    const float C1 = 0.923879532511286756f;
    const float S1 = 0.382683432365089772f;
    const float R2 = 0.707106781186547524f;
    const float G = (SGN < 0) ? -1.0f : 1.0f;
    w[5]  = cmul(w[5],  make_float2( C1,  G*S1));
    w[6]  = cmul(w[6],  make_float2( R2,  G*R2));
    w[7]  = cmul(w[7],  make_float2( S1,  G*C1));
    w[9]  = cmul(w[9],  make_float2( R2,  G*R2));
    w[10] = (SGN<0) ? mul_mi(w[10]) : mul_i(w[10]);
    w[11] = cmul(w[11], make_float2(-R2,  G*R2));
    w[13] = cmul(w[13], make_float2( S1,  G*C1));
    w[14] = cmul(w[14], make_float2(-R2,  G*R2));
    w[15] = cmul(w[15], make_float2(-C1, -G*S1));
    #pragma unroll
    for (int k0 = 0; k0 < 4; ++k0){
        float2 a = w[k0*4+0], b = w[k0*4+1], c = w[k0*4+2], d = w[k0*4+3];
        float2 t0 = cadd(a,c), t1 = csub(a,c), t2 = cadd(b,d), t3 = csub(b,d);
        float2 j3 = (SGN < 0) ? mul_mi(t3) : mul_i(t3);
        v[k0]    = cadd(t0,t2);
        v[k0+4]  = cadd(t1,j3);
        v[k0+8]  = csub(t0,t2);
        v[k0+12] = csub(t1,j3);
    }
}

template<int SGN>
__device__ __forceinline__ void dft16(float2 v[16]){
    float2 w[16];
    #pragma unroll
    for (int n0 = 0; n0 < 4; ++n0){
        float2 a = v[n0], b = v[n0+4], c = v[n0+8], d = v[n0+12];
        float2 t0 = cadd(a,c), t1 = csub(a,c), t2 = cadd(b,d), t3 = csub(b,d);
        float2 j3 = (SGN < 0) ? mul_mi(t3) : mul_i(t3);
        w[n0]    = cadd(t0,t2);
        w[4+n0]  = cadd(t1,j3);
        w[8+n0]  = csub(t0,t2);
        w[12+n0] = csub(t1,j3);
    }
    dft16_tail<SGN>(w, v);
}

// forward DFT16 with inputs 8..15 == 0 (zero-padded), SGN=-1
__device__ __forceinline__ void dft16_zero8(float2 v[16]){
    float2 w[16];
    #pragma unroll
    for (int n0 = 0; n0 < 4; ++n0){
        float2 a = v[n0], b = v[n0+4];
        w[n0]    = cadd(a,b);
        w[4+n0]  = make_float2(a.x + b.y, a.y - b.x);  // a - i b
        w[8+n0]  = csub(a,b);
        w[12+n0] = make_float2(a.x - b.y, a.y + b.x);  // a + i b
    }
    dft16_tail<-1>(w, v);
}

// ---------- in-place dft16, digit-reversed output: slot s holds y[4*(s&3)+(s>>2)].
template<int SGN>
__device__ __forceinline__ void dft16_ip(float2 v[16]){
    const float C1 = 0.923879532511286756f;
    const float S1 = 0.382683432365089772f;
    const float R2 = 0.707106781186547524f;
    const float G = (SGN < 0) ? -1.0f : 1.0f;
    #pragma unroll
    for (int n1 = 0; n1 < 4; ++n1){
        float2 a = v[n1], b = v[n1+4], c = v[n1+8], d = v[n1+12];
        float2 t0 = cadd(a,c), t1 = csub(a,c), t2 = cadd(b,d), t3 = csub(b,d);
        float2 j3 = (SGN < 0) ? mul_mi(t3) : mul_i(t3);
        v[n1]    = cadd(t0,t2);
        v[n1+4]  = cadd(t1,j3);
        v[n1+8]  = csub(t0,t2);
        v[n1+12] = csub(t1,j3);
    }
    v[5]  = cmul(v[5],  make_float2( C1,  G*S1));
    v[6]  = cmul(v[6],  make_float2( R2,  G*R2));
    v[7]  = cmul(v[7],  make_float2( S1,  G*C1));
    v[9]  = cmul(v[9],  make_float2( R2,  G*R2));
    v[10] = (SGN<0) ? mul_mi(v[10]) : mul_i(v[10]);
    v[11] = cmul(v[11], make_float2(-R2,  G*R2));
    v[13] = cmul(v[13], make_float2( S1,  G*C1));
    v[14] = cmul(v[14], make_float2(-R2,  G*R2));
    v[15] = cmul(v[15], make_float2(-C1, -G*S1));
    #pragma unroll
    for (int kl = 0; kl < 4; ++kl){
        float2 a = v[4*kl], b = v[4*kl+1], c = v[4*kl+2], d = v[4*kl+3];
        float2 t0 = cadd(a,c), t1 = csub(a,c), t2 = cadd(b,d), t3 = csub(b,d);
        float2 j3 = (SGN < 0) ? mul_mi(t3) : mul_i(t3);
        v[4*kl]   = cadd(t0,t2);
        v[4*kl+1] = cadd(t1,j3);
        v[4*kl+2] = csub(t0,t2);
        v[4*kl+3] = csub(t1,j3);
    }
}

template<int SGN>
__device__ __forceinline__ void twchain16(float2 v[16], float theta){
    float th = (SGN < 0) ? -theta : theta;
    float s1,c1; __sincosf(th, &s1, &c1);
    float s4,c4; __sincosf(4.0f*th, &s4, &c4);
    float2 w1 = make_float2(c1,s1), w4 = make_float2(c4,s4);
    float2 lo2 = cmul(w1,w1), lo3 = cmul(lo2,w1);
    float2 hi2 = cmul(w4,w4), hi3 = cmul(hi2,w4);
    float2 lo[4] = {make_float2(1.f,0.f), w1, lo2, lo3};
    float2 hi[4] = {make_float2(1.f,0.f), w4, hi2, hi3};
    #pragma unroll
    for (int s = 1; s < 16; ++s){
        v[s] = cmul(v[s], cmul(hi[s>>2], lo[s&3]));
    }
}

__device__ __forceinline__ int L1swz(int e){
    return (e & ~63) | (((e & 63) + ((e >> 6) & 15)) & 63);
}

// F1 (stage A): 128 blocks = 32 m x 4 col-groups, 256 threads, 1 column/thread.
// Block 0 thread 0 also zeroes the pair-completion counter for this call.
__global__ __launch_bounds__(256, 1) void stageA_kernel(const float* __restrict__ x,
                                                        unsigned* __restrict__ mid,
                                                        unsigned* __restrict__ done_ctr) {
    const int bx = blockIdx.x, m = bx >> 2, grp = bx & 3;
    if (bx == 0 && threadIdx.x == 0) *done_ctr = 0u;
    const int j = grp*256 + threadIdx.x;      // column 0..1023
    float2 v[16];
    #pragma unroll
    for (int s = 0; s < 8; ++s){
        float ph = TWOPI_F * x[m*NLEN + s*1024 + j];
        float sn,cs; __sincosf(ph,&sn,&cs);
        v[s] = make_float2(cs,sn);
    }
    dft16_zero8(v);
    twchain16<-1>(v, TWOPI_F * (float)j / 16384.0f);
    unsigned* dst = mid + (size_t)m*FFT_N + L1swz(j);
    #pragma unroll
    for (int s = 0; s < 16; ++s) dst[s*1024] = pkc(v[s]);
}

// F2 (stages B+C): 128 blocks = 32 m x 4 chunk-groups, 256 threads, wave = chunk.
__global__ __launch_bounds__(256, 1) void bc_kernel(const unsigned* __restrict__ mid,
                                                    unsigned* __restrict__ spec) {
    __shared__ float2 X[4096];  // 32 KiB
    const int bx = blockIdx.x, m = bx >> 2, g = bx & 3;
    const int tid = threadIdx.x;
    const int wv = tid >> 6, jB = tid & 63;
    const int ch = g*4 + wv;
    const unsigned* base = mid + (size_t)m*FFT_N + ch*1024;
    float2 v[16];

    #pragma unroll
    for (int t = 0; t < 16; ++t) v[t] = upkc(base[t*64 + ((jB + t) & 63)]);
    dft16<-1>(v);
    twchain16<-1>(v, TWOPI_F * (float)jB / 1024.0f);
    #pragma unroll
    for (int sp = 0; sp < 16; ++sp) X[wv*1024 + sp*64 + ((jB + 4*sp) & 63)] = v[sp];
    // no barrier: stage C reads only this wave's region

    {
        const int bl = (tid & 63) >> 2, jC = tid & 3;
        #pragma unroll
        for (int a = 0; a < 16; ++a)
            v[a] = X[wv*1024 + bl*64 + ((4*a + jC + 4*bl) & 63)];
        dft16<-1>(v);
        twchain16<-1>(v, TWOPI_F * (float)jC / 64.0f);
        const bool odd1 = (jC & 1) != 0;
        const bool odd2 = (jC & 2) != 0;
        #pragma unroll
        for (int e = 0; e < 16; ++e){
            float2 p = dpp_xor2(v[e]);
            float2 t = odd2 ? csub(p, v[e]) : cadd(v[e], p);
            float2 q = dpp_xor1(t);
            float2 re = odd1 ? csub(q, t) : cadd(t, q);
            float2 ro = odd1 ? cadd(q, mul_i(t)) : cadd(t, mul_mi(q));
            v[e] = odd2 ? ro : re;
        }
        const int u = ((jC & 1) << 1) | (jC >> 1);
        uint4* dst = (uint4*)(spec + (size_t)m*FFT_N + ch*1024 + bl*64 + u*16);
        #pragma unroll
        for (int e = 0; e < 4; ++e)
            dst[e] = make_uint4(pkc(v[4*e]), pkc(v[4*e+1]), pkc(v[4*e+2]), pkc(v[4*e+3]));
    }
}

// Pair kernel: 512 blocks; R14-verified body; the LAST block to finish (device-
// scope atomic counter) additionally performs the final merge -> out. The merge
// result is deterministic regardless of which block runs it.
__global__ __launch_bounds__(512, 4) void pair_kernel(const unsigned* __restrict__ spec,
                                                      float4* __restrict__ rec,
                                                      unsigned* __restrict__ done_ctr,
                                                      float* __restrict__ out) {
    __shared__ unsigned X[FFT_N];  // 64 KiB, bf16x2 per element
    __shared__ float scr2[64];
    __shared__ int lastFlag;
    const int r = blockIdx.x, tid = threadIdx.x;
    const bool is_packed = (r >= 496);
    int a, b;
    if (is_packed){
        const int k = r - 496; a = 2*k; b = 2*k + 1;
    } else {
        int t = r; a = 0; int rem = M_WAVE - 1;
        while (t >= rem){ t -= rem; ++a; rem = M_WAVE - 1 - a; }
        b = a + 1 + t;
    }
    const int jC = tid & 3;
    const int u = ((jC & 1) << 1) | (jC >> 1);
    const bool odd1 = (jC & 1) != 0;
    const bool odd2 = (jC & 2) != 0;

    // Stage C' (both passes)
    #pragma unroll
    for (int p = 0; p < 2; ++p){
        const int blk = (tid >> 2) + 128*p;   // [0,256)
        float2 v[16];
        const uint4* pa = (const uint4*)(spec + (size_t)a*FFT_N + blk*64 + u*16);
        const uint4* pb = (const uint4*)(spec + (size_t)b*FFT_N + blk*64 + u*16);
        #pragma unroll
        for (int e = 0; e < 4; ++e){
            uint4 A = pa[e], B = pb[e];
            float2 a0 = upkc(A.x), a1 = upkc(A.y), a2 = upkc(A.z), a3 = upkc(A.w);
            float2 b0 = upkc(B.x), b1 = upkc(B.y), b2 = upkc(B.z), b3 = upkc(B.w);
            if (is_packed){
                v[4*e+0] = make_float2(a0.x*a0.x + a0.y*a0.y, b0.x*b0.x + b0.y*b0.y);
                v[4*e+1] = make_float2(a1.x*a1.x + a1.y*a1.y, b1.x*b1.x + b1.y*b1.y);
                v[4*e+2] = make_float2(a2.x*a2.x + a2.y*a2.y, b2.x*b2.x + b2.y*b2.y);
                v[4*e+3] = make_float2(a3.x*a3.x + a3.y*a3.y, b3.x*b3.x + b3.y*b3.y);
            } else {
                v[4*e+0] = make_float2(b0.x*a0.x + b0.y*a0.y, b0.y*a0.x - b0.x*a0.y);
                v[4*e+1] = make_float2(b1.x*a1.x + b1.y*a1.y, b1.y*a1.x - b1.x*a1.y);
                v[4*e+2] = make_float2(b2.x*a2.x + b2.y*a2.y, b2.y*a2.x - b2.x*a2.y);
                v[4*e+3] = make_float2(b3.x*a3.x + b3.y*a3.y, b3.y*a3.x - b3.x*a3.y);
            }
        }
        #pragma unroll
        for (int e = 0; e < 16; ++e){
            float2 q = dpp_xor1(v[e]);
            float2 t = odd1 ? csub(q, v[e]) : cadd(v[e], q);
            float2 pp = dpp_xor2(t);
            float2 re = odd2 ? csub(pp, t) : cadd(t, pp);
            float2 ro = odd2 ? csub(pp, mul_i(t)) : cadd(t, mul_i(pp));
            v[e] = odd1 ? ro : re;
        }
        twchain16<+1>(v, TWOPI_F * (float)jC / 64.0f);
        dft16_ip<+1>(v);
        const int rot = 4*(blk & 15);
        #pragma unroll
        for (int s = 0; s < 16; ++s){
            const int t = 4*(s&3) + (s>>2);   // digit held in slot s
            X[blk*64 + ((4*t + jC + rot) & 63)] = pkc(v[s]);
        }
    }
    // Stage B' (both passes; wave-local)
    const int wv = tid >> 6, jB = tid & 63;
    #pragma unroll
    for (int p = 0; p < 2; ++p){
        const int sB = wv + 8*p;
        float2 v[16];
        #pragma unroll
        for (int sp = 0; sp < 16; ++sp) v[sp] = upkc(X[sB*1024 + sp*64 + ((jB + 4*sp) & 63)]);
        twchain16<+1>(v, TWOPI_F * (float)jB / 1024.0f);
        dft16_ip<+1>(v);
        #pragma unroll
        for (int s = 0; s < 16; ++s){
            const int t = 4*(s&3) + (s>>2);
            X[sB*1024 + t*64 + ((jB + t) & 63)] = pkc(v[s]);
        }
    }
    __syncthreads();   // cross-wave: A' gathers from all chunks

    const float CSCALE = 0.1f / (16384.0f * 16384.0f);
    const float invTN2 = 1.0f / 67108.864f;   // 1/(T*N*N)
    const int lane = tid & 63, wvv = tid >> 6;   // 8 waves

    if (!is_packed){
        // single-pass stats: max, sum, direct expsum
        float lm = 0.f, lsum = 0.f, le = 0.f;
        #pragma unroll
        for (int p = 0; p < 2; ++p){
            const int tp = tid + 512*p;
            const int baseA = L1swz(tp);
            float2 v[16];
            #pragma unroll
            for (int s = 0; s < 16; ++s) v[s] = upkc(X[s*1024 + baseA]);
            twchain16<+1>(v, TWOPI_F * (float)tp / 16384.0f);
            dft16_ip<+1>(v);
            const bool j0 = (tp == 0);
            #pragma unroll
            for (int s = 0; s < 16; ++s){
                const int t = 4*(s&3) + (s>>2);
                float uu = CSCALE * (v[s].x*v[s].x + v[s].y*v[s].y);
                bool inv = (t == 8) && j0;
                if (!inv){
                    lm = fmaxf(lm, uu); lsum += uu;
                    float w0 = (t == 0 && j0) ? 2.f : 1.f;
                    le += w0 * __expf(uu * invTN2);
                }
                if (t == 0 && j0) lsum += uu;
            }
        }
        __syncthreads();  // X reads done; reuse as scratch

        float* scratch = (float*)X;
        float wm = waveReduceMax(lm);
        float wsm = waveReduceSum(lsum);
        float wle = waveReduceSum(le);
        if (lane == 0){ scratch[wvv] = wm; scratch[8+wvv] = wsm; scratch[16+wvv] = wle; }
        __syncthreads();
        if (tid == 0){
            float m_b = scratch[0], sumu = scratch[8], sb2 = scratch[16];
            #pragma unroll
            for (int i = 1; i < 8; ++i){
                m_b = fmaxf(m_b, scratch[i]); sumu += scratch[8+i]; sb2 += scratch[16+i];
            }
            rec[M_WAVE + r] = make_float4(m_b, sumu, sb2, 0.f);
        }
    } else {
        // packed autos: A', store z lag-indexed, one stats pass with partner read
        unsigned zpk[2][16];
        #pragma unroll
        for (int p = 0; p < 2; ++p){
            const int tp = tid + 512*p;
            const int baseA = L1swz(tp);
            float2 v[16];
            #pragma unroll
            for (int s = 0; s < 16; ++s) v[s] = upkc(X[s*1024 + baseA]);
            twchain16<+1>(v, TWOPI_F * (float)tp / 16384.0f);
            dft16_ip<+1>(v);
            #pragma unroll
            for (int s = 0; s < 16; ++s) zpk[p][s] = pkc(v[s]);
        }
        __syncthreads();  // all A' reads of X complete
        #pragma unroll
        for (int p = 0; p < 2; ++p){
            const int tp = tid + 512*p;
            #pragma unroll
            for (int s = 0; s < 16; ++s){
                const int t = 4*(s&3) + (s>>2);
                X[t*1024 + tp] = zpk[p][s];    // lag-indexed bf16 z
            }
        }
        __syncthreads();

        float lma = 0.f, lmb = 0.f, lsa = 0.f, lsb = 0.f, lea = 0.f, leb = 0.f;
        #pragma unroll
        for (int p = 0; p < 2; ++p){
            const int tp = tid + 512*p;
            #pragma unroll
            for (int s = 0; s < 16; ++s){
                const int t = 4*(s&3) + (s>>2);
                if (t < 8) continue;
                if (t == 8 && tp == 0) continue;
                const int n = t*1024 + tp;
                float2 z  = upkc(X[n]);
                float2 zc = upkc(X[FFT_N - n]);
                float ar = 0.5f*(z.x + zc.x), ai = 0.5f*(z.y - zc.y);
                float br = 0.5f*(z.x - zc.x), bi = 0.5f*(z.y + zc.y);
                float ua = CSCALE*(ar*ar + ai*ai);
                float ub = CSCALE*(br*br + bi*bi);
                lma = fmaxf(lma, ua); lsa += ua; lea += __expf(ua * invTN2);
                lmb = fmaxf(lmb, ub); lsb += ub; leb += __expf(ub * invTN2);
            }
        }
        float wma = waveReduceMax(lma), wmb = waveReduceMax(lmb);
        float wsa = waveReduceSum(lsa), wsb = waveReduceSum(lsb);
        float wea = waveReduceSum(lea), web = waveReduceSum(leb);
        if (lane == 0){
            scr2[wvv]=wma; scr2[8+wvv]=wmb; scr2[16+wvv]=wsa;
            scr2[24+wvv]=wsb; scr2[32+wvv]=wea; scr2[40+wvv]=web;
        }
        __syncthreads();
        if (tid == 0){
            float m_a = scr2[0], m_b = scr2[8], s_a = scr2[16], s_b = scr2[24];
            float e_a = scr2[32], e_b = scr2[40];
            #pragma unroll
            for (int i = 1; i < 8; ++i){
                m_a = fmaxf(m_a, scr2[i]);    m_b = fmaxf(m_b, scr2[8+i]);
                s_a += scr2[16+i];            s_b += scr2[24+i];
                e_a += scr2[32+i];            e_b += scr2[40+i];
            }
            const int k = r - 496;
            rec[2*k]   = make_float4(m_a, s_a, e_a, 0.f);
            rec[2*k+1] = make_float4(m_b, s_b, e_b, 0.f);
        }
    }

    // -------- fused final merge: last block to arrive does it --------
    __syncthreads();           // rec write (tid 0) ordered before the tail
    if (tid == 0){
        __threadfence();       // release: make this block's rec visible device-wide
        unsigned old = atomicAdd(done_ctr, 1u);
        lastFlag = (old == 511u) ? 1 : 0;
    }
    __syncthreads();
    if (lastFlag){
        __threadfence();       // acquire: see all other blocks' rec writes
        if (tid < 64){
            const int ln = tid;
            float mA = 0.f, mC = 0.f;
            double S = 0.0, sA = 0.0, sC = 0.0;
            for (int rr = ln; rr < NPAIR; rr += 64){
                float4 rv = rec[rr];
                S += (double)rv.z;
                if (rr < M_WAVE){ mA = fmaxf(mA, rv.x); sA += (double)rv.y; }
                else            { mC = fmaxf(mC, rv.x); sC += (double)rv.y; }
            }
            #pragma unroll
            for (int off = 32; off > 0; off >>= 1){
                mA = fmaxf(mA, __shfl_xor(mA, off, 64));
                mC = fmaxf(mC, __shfl_xor(mC, off, 64));
                S  += __shfl_xor(S,  off, 64);
                sA += __shfl_xor(sA, off, 64);
                sC += __shfl_xor(sC, off, 64);
            }
            if (ln == 0){
                const double invN2 = 1.0/67108864.0;
                const float Mall = fmaxf(mA, mC);
                out[0] = (float)(1e-3 * log(S));
                out[1] = (float)((double)Mall*invN2);
                out[2] = mA;
                out[3] = mC;
                out[4] = (float)((sA + sC)*invN2);
                out[5] = (float)sA;
                out[6] = (float)sC;
            }
        }
    }
}

extern "C" void kernel_launch(void* const* d_in, const int* in_sizes, int n_in,
                              void* d_out, int out_size, void* d_ws, size_t ws_size,
                              hipStream_t stream) {
    (void)in_sizes; (void)n_in; (void)out_size; (void)ws_size;
    const float* x = (const float*)d_in[0];
    float* out = (float*)d_out;

    unsigned* spec = (unsigned*)d_ws;                                   // 2 MiB
    float4* rec = (float4*)((char*)d_ws + (size_t)M_WAVE * FFT_N * 4);  // 8448 B
    unsigned* mid = (unsigned*)((char*)d_ws + (size_t)M_WAVE * FFT_N * 4
                                + (size_t)NPAIR * sizeof(float4));      // 2 MiB
    unsigned* done_ctr = (unsigned*)((char*)d_ws + (size_t)M_WAVE * FFT_N * 4
                                     + (size_t)NPAIR * sizeof(float4)
                                     + (size_t)M_WAVE * FFT_N * 4);     // 4 B

    stageA_kernel<<<128, 256, 0, stream>>>(x, mid, done_ctr);
    bc_kernel<<<128, 256, 0, stream>>>(mid, spec);
    pair_kernel<<<512, 512, 0, stream>>>(spec, rec, done_ctr, out);
}

// Round 17
// 47.888 us; speedup vs baseline: 1.1187x; 1.1187x over previous
//
#include <hip/hip_runtime.h>
#include <math.h>

#define M_WAVE 32
#define NLEN 8192
#define FFT_N 16384
#define NPAIR 528   // rec entries: 32 autos (rec[0..31]) + 496 cross (rec[32..527])

#define TWOPI_F 6.28318530717958647692f

__device__ __forceinline__ float2 cadd(float2 a, float2 b){return make_float2(a.x+b.x, a.y+b.y);}
__device__ __forceinline__ float2 csub(float2 a, float2 b){return make_float2(a.x-b.x, a.y-b.y);}
__device__ __forceinline__ float2 cmul(float2 a, float2 b){return make_float2(a.x*b.x-a.y*b.y, a.x*b.y+a.y*b.x);}
__device__ __forceinline__ float2 mul_i (float2 a){return make_float2(-a.y,  a.x);}
__device__ __forceinline__ float2 mul_mi(float2 a){return make_float2( a.y, -a.x);}

// bf16x2 pack/unpack: one complex float2 <-> one u32 (re=low16, im=high16)
__device__ __forceinline__ unsigned pkc(float2 v){
    unsigned r;
    asm("v_cvt_pk_bf16_f32 %0, %1, %2" : "=v"(r) : "v"(v.x), "v"(v.y));
    return r;
}
__device__ __forceinline__ float2 upkc(unsigned u){
    return make_float2(__uint_as_float(u << 16), __uint_as_float(u & 0xFFFF0000u));
}

__device__ __forceinline__ float2 dpp_xor1(float2 v){
    float2 r;
    r.x = __int_as_float(__builtin_amdgcn_mov_dpp(__float_as_int(v.x), 0xB1, 0xF, 0xF, true));
    r.y = __int_as_float(__builtin_amdgcn_mov_dpp(__float_as_int(v.y), 0xB1, 0xF, 0xF, true));
    return r;
}
__device__ __forceinline__ float2 dpp_xor2(float2 v){
    float2 r;
    r.x = __int_as_float(__builtin_amdgcn_mov_dpp(__float_as_int(v.x), 0x4E, 0xF, 0xF, true));
    r.y = __int_as_float(__builtin_amdgcn_mov_dpp(__float_as_int(v.y), 0x4E, 0xF, 0xF, true));
    return r;
}

__device__ __forceinline__ float waveReduceMax(float v) {
    #pragma unroll
    for (int off = 32; off > 0; off >>= 1) v = fmaxf(v, __shfl_down(v, off, 64));
    return v;
}
__device__ __forceinline__ float waveReduceSum(float v) {
    #pragma unroll
    for (int off = 32; off > 0; off >>= 1) v += __shfl_down(v, off, 64);
    return v;
}

// ---------- classic dft16 (natural order) ----------
template<int SGN>
__device__ __forceinline__ void dft16_tail(float2 w[16], float2 v[16]){
    const float C1 = 0.923879532511286756f;
    const float S1 = 0.382683432365089772f;
    const float R2 = 0.707106781186547524f;
    const float G = (SGN < 0) ? -1.0f : 1.0f;
    w[5]  = cmul(w[5],  make_float2( C1,  G*S1));
    w[6]  = cmul(w[6],  make_float2( R2,  G*R2));
    w[7]  = cmul(w[7],  make_float2( S1,  G*C1));
    w[9]  = cmul(w[9],  make_float2( R2,  G*R2));
    w[10] = (SGN<0) ? mul_mi(w[10]) : mul_i(w[10]);
    w[11] = cmul(w[11], make_float2(-R2,  G*R2));
    w[13] = cmul(w[13], make_float2( S1,  G*C1));
    w[14] = cmul(w[14], make_float2(-R2,  G*R2));
    w[15] = cmul(w[15], make_float2(-C1, -G*S1));
    #pragma unroll
    for (int k0 = 0; k0 < 4; ++k0){
        float2 a = w[k0*4+0], b = w[k0*4+1], c = w[k0*4+2], d = w[k0*4+3];
        float2 t0 = cadd(a,c), t1 = csub(a,c), t2 = cadd(b,d), t3 = csub(b,d);
        float2 j3 = (SGN < 0) ? mul_mi(t3) : mul_i(t3);
        v[k0]    = cadd(t0,t2);
        v[k0+4]  = cadd(t1,j3);
        v[k0+8]  = csub(t0,t2);
        v[k0+12] = csub(t1,j3);
    }
}

template<int SGN>
__device__ __forceinline__ void dft16(float2 v[16]){
    float2 w[16];
    #pragma unroll
    for (int n0 = 0; n0 < 4; ++n0){
        float2 a = v[n0], b = v[n0+4], c = v[n0+8], d = v[n0+12];
        float2 t0 = cadd(a,c), t1 = csub(a,c), t2 = cadd(b,d), t3 = csub(b,d);
        float2 j3 = (SGN < 0) ? mul_mi(t3) : mul_i(t3);
        w[n0]    = cadd(t0,t2);
        w[4+n0]  = cadd(t1,j3);
        w[8+n0]  = csub(t0,t2);
        w[12+n0] = csub(t1,j3);
    }
    dft16_tail<SGN>(w, v);
}

// forward DFT16 with inputs 8..15 == 0 (zero-padded), SGN=-1
__device__ __forceinline__ void dft16_zero8(float2 v[16]){
    float2 w[16];
    #pragma unroll
    for (int n0 = 0; n0 < 4; ++n0){
        float2 a = v[n0], b = v[n0+4];
        w[n0]    = cadd(a,b);
        w[4+n0]  = make_float2(a.x + b.y, a.y - b.x);  // a - i b
        w[8+n0]  = csub(a,b);
        w[12+n0] = make_float2(a.x - b.y, a.y + b.x);  // a + i b
    }
    dft16_tail<-1>(w, v);
}

// ---------- in-place dft16, digit-reversed output: slot s holds y[4*(s&3)+(s>>2)].
template<int SGN>
__device__ __forceinline__ void dft16_ip(float2 v[16]){
    const float C1 = 0.923879532511286756f;
    const float S1 = 0.382683432365089772f;
    const float R2 = 0.707106781186547524f;
    const float G = (SGN < 0) ? -1.0f : 1.0f;
    #pragma unroll
    for (int n1 = 0; n1 < 4; ++n1){
        float2 a = v[n1], b = v[n1+4], c = v[n1+8], d = v[n1+12];
        float2 t0 = cadd(a,c), t1 = csub(a,c), t2 = cadd(b,d), t3 = csub(b,d);
        float2 j3 = (SGN < 0) ? mul_mi(t3) : mul_i(t3);
        v[n1]    = cadd(t0,t2);
        v[n1+4]  = cadd(t1,j3);
        v[n1+8]  = csub(t0,t2);
        v[n1+12] = csub(t1,j3);
    }
    v[5]  = cmul(v[5],  make_float2( C1,  G*S1));
    v[6]  = cmul(v[6],  make_float2( R2,  G*R2));
    v[7]  = cmul(v[7],  make_float2( S1,  G*C1));
    v[9]  = cmul(v[9],  make_float2( R2,  G*R2));
    v[10] = (SGN<0) ? mul_mi(v[10]) : mul_i(v[10]);
    v[11] = cmul(v[11], make_float2(-R2,  G*R2));
    v[13] = cmul(v[13], make_float2( S1,  G*C1));
    v[14] = cmul(v[14], make_float2(-R2,  G*R2));
    v[15] = cmul(v[15], make_float2(-C1, -G*S1));
    #pragma unroll
    for (int kl = 0; kl < 4; ++kl){
        float2 a = v[4*kl], b = v[4*kl+1], c = v[4*kl+2], d = v[4*kl+3];
        float2 t0 = cadd(a,c), t1 = csub(a,c), t2 = cadd(b,d), t3 = csub(b,d);
        float2 j3 = (SGN < 0) ? mul_mi(t3) : mul_i(t3);
        v[4*kl]   = cadd(t0,t2);
        v[4*kl+1] = cadd(t1,j3);
        v[4*kl+2] = csub(t0,t2);
        v[4*kl+3] = csub(t1,j3);
    }
}

template<int SGN>
__device__ __forceinline__ void twchain16(float2 v[16], float theta){
    float th = (SGN < 0) ? -theta : theta;
    float s1,c1; __sincosf(th, &s1, &c1);
    float s4,c4; __sincosf(4.0f*th, &s4, &c4);
    float2 w1 = make_float2(c1,s1), w4 = make_float2(c4,s4);
    float2 lo2 = cmul(w1,w1), lo3 = cmul(lo2,w1);
    float2 hi2 = cmul(w4,w4), hi3 = cmul(hi2,w4);
    float2 lo[4] = {make_float2(1.f,0.f), w1, lo2, lo3};
    float2 hi[4] = {make_float2(1.f,0.f), w4, hi2, hi3};
    #pragma unroll
    for (int s = 1; s < 16; ++s){
        v[s] = cmul(v[s], cmul(hi[s>>2], lo[s&3]));
    }
}

__device__ __forceinline__ int L1swz(int e){
    return (e & ~63) | (((e & 63) + ((e >> 6) & 15)) & 63);
}

// F1 (stage A): 128 blocks = 32 m x 4 col-groups, 256 threads, 1 column/thread.
__global__ __launch_bounds__(256, 1) void stageA_kernel(const float* __restrict__ x,
                                                        unsigned* __restrict__ mid) {
    const int bx = blockIdx.x, m = bx >> 2, grp = bx & 3;
    const int j = grp*256 + threadIdx.x;      // column 0..1023
    float2 v[16];
    #pragma unroll
    for (int s = 0; s < 8; ++s){
        float ph = TWOPI_F * x[m*NLEN + s*1024 + j];
        float sn,cs; __sincosf(ph,&sn,&cs);
        v[s] = make_float2(cs,sn);
    }
    dft16_zero8(v);
    twchain16<-1>(v, TWOPI_F * (float)j / 16384.0f);
    unsigned* dst = mid + (size_t)m*FFT_N + L1swz(j);
    #pragma unroll
    for (int s = 0; s < 16; ++s) dst[s*1024] = pkc(v[s]);
}

// F2 (stages B+C): 128 blocks = 32 m x 4 chunk-groups, 256 threads, wave = chunk.
__global__ __launch_bounds__(256, 1) void bc_kernel(const unsigned* __restrict__ mid,
                                                    unsigned* __restrict__ spec) {
    __shared__ float2 X[4096];  // 32 KiB
    const int bx = blockIdx.x, m = bx >> 2, g = bx & 3;
    const int tid = threadIdx.x;
    const int wv = tid >> 6, jB = tid & 63;
    const int ch = g*4 + wv;
    const unsigned* base = mid + (size_t)m*FFT_N + ch*1024;
    float2 v[16];

    #pragma unroll
    for (int t = 0; t < 16; ++t) v[t] = upkc(base[t*64 + ((jB + t) & 63)]);
    dft16<-1>(v);
    twchain16<-1>(v, TWOPI_F * (float)jB / 1024.0f);
    #pragma unroll
    for (int sp = 0; sp < 16; ++sp) X[wv*1024 + sp*64 + ((jB + 4*sp) & 63)] = v[sp];
    // no barrier: stage C reads only this wave's region

    {
        const int bl = (tid & 63) >> 2, jC = tid & 3;
        #pragma unroll
        for (int a = 0; a < 16; ++a)
            v[a] = X[wv*1024 + bl*64 + ((4*a + jC + 4*bl) & 63)];
        dft16<-1>(v);
        twchain16<-1>(v, TWOPI_F * (float)jC / 64.0f);
        const bool odd1 = (jC & 1) != 0;
        const bool odd2 = (jC & 2) != 0;
        #pragma unroll
        for (int e = 0; e < 16; ++e){
            float2 p = dpp_xor2(v[e]);
            float2 t = odd2 ? csub(p, v[e]) : cadd(v[e], p);
            float2 q = dpp_xor1(t);
            float2 re = odd1 ? csub(q, t) : cadd(t, q);
            float2 ro = odd1 ? cadd(q, mul_i(t)) : cadd(t, mul_mi(q));
            v[e] = odd2 ? ro : re;
        }
        const int u = ((jC & 1) << 1) | (jC >> 1);
        uint4* dst = (uint4*)(spec + (size_t)m*FFT_N + ch*1024 + bl*64 + u*16);
        #pragma unroll
        for (int e = 0; e < 4; ++e)
            dst[e] = make_uint4(pkc(v[4*e]), pkc(v[4*e+1]), pkc(v[4*e+2]), pkc(v[4*e+3]));
    }
}

// Pair kernel: 512 blocks; R11-verified network; computed twiddles (R12);
// single-pass stats with direct exp (no max subtraction; exp args << 1).
__global__ __launch_bounds__(512, 4) void pair_kernel(const unsigned* __restrict__ spec,
                                                      float4* __restrict__ rec) {
    __shared__ unsigned X[FFT_N];  // 64 KiB, bf16x2 per element
    __shared__ float scr2[64];
    const int r = blockIdx.x, tid = threadIdx.x;
    const bool is_packed = (r >= 496);
    int a, b;
    if (is_packed){
        const int k = r - 496; a = 2*k; b = 2*k + 1;
    } else {
        int t = r; a = 0; int rem = M_WAVE - 1;
        while (t >= rem){ t -= rem; ++a; rem = M_WAVE - 1 - a; }
        b = a + 1 + t;
    }
    const int jC = tid & 3;
    const int u = ((jC & 1) << 1) | (jC >> 1);
    const bool odd1 = (jC & 1) != 0;
    const bool odd2 = (jC & 2) != 0;

    // Stage C' (both passes)
    #pragma unroll
    for (int p = 0; p < 2; ++p){
        const int blk = (tid >> 2) + 128*p;   // [0,256)
        float2 v[16];
        const uint4* pa = (const uint4*)(spec + (size_t)a*FFT_N + blk*64 + u*16);
        const uint4* pb = (const uint4*)(spec + (size_t)b*FFT_N + blk*64 + u*16);
        #pragma unroll
        for (int e = 0; e < 4; ++e){
            uint4 A = pa[e], B = pb[e];
            float2 a0 = upkc(A.x), a1 = upkc(A.y), a2 = upkc(A.z), a3 = upkc(A.w);
            float2 b0 = upkc(B.x), b1 = upkc(B.y), b2 = upkc(B.z), b3 = upkc(B.w);
            if (is_packed){
                v[4*e+0] = make_float2(a0.x*a0.x + a0.y*a0.y, b0.x*b0.x + b0.y*b0.y);
                v[4*e+1] = make_float2(a1.x*a1.x + a1.y*a1.y, b1.x*b1.x + b1.y*b1.y);
                v[4*e+2] = make_float2(a2.x*a2.x + a2.y*a2.y, b2.x*b2.x + b2.y*b2.y);
                v[4*e+3] = make_float2(a3.x*a3.x + a3.y*a3.y, b3.x*b3.x + b3.y*b3.y);
            } else {
                v[4*e+0] = make_float2(b0.x*a0.x + b0.y*a0.y, b0.y*a0.x - b0.x*a0.y);
                v[4*e+1] = make_float2(b1.x*a1.x + b1.y*a1.y, b1.y*a1.x - b1.x*a1.y);
                v[4*e+2] = make_float2(b2.x*a2.x + b2.y*a2.y, b2.y*a2.x - b2.x*a2.y);
                v[4*e+3] = make_float2(b3.x*a3.x + b3.y*a3.y, b3.y*a3.x - b3.x*a3.y);
            }
        }
        #pragma unroll
        for (int e = 0; e < 16; ++e){
            float2 q = dpp_xor1(v[e]);
            float2 t = odd1 ? csub(q, v[e]) : cadd(v[e], q);
            float2 pp = dpp_xor2(t);
            float2 re = odd2 ? csub(pp, t) : cadd(t, pp);
            float2 ro = odd2 ? csub(pp, mul_i(t)) : cadd(t, mul_i(pp));
            v[e] = odd1 ? ro : re;
        }
        twchain16<+1>(v, TWOPI_F * (float)jC / 64.0f);
        dft16_ip<+1>(v);
        const int rot = 4*(blk & 15);
        #pragma unroll
        for (int s = 0; s < 16; ++s){
            const int t = 4*(s&3) + (s>>2);   // digit held in slot s
            X[blk*64 + ((4*t + jC + rot) & 63)] = pkc(v[s]);
        }
    }
    // Stage B' (both passes; wave-local)
    const int wv = tid >> 6, jB = tid & 63;
    #pragma unroll
    for (int p = 0; p < 2; ++p){
        const int sB = wv + 8*p;
        float2 v[16];
        #pragma unroll
        for (int sp = 0; sp < 16; ++sp) v[sp] = upkc(X[sB*1024 + sp*64 + ((jB + 4*sp) & 63)]);
        twchain16<+1>(v, TWOPI_F * (float)jB / 1024.0f);
        dft16_ip<+1>(v);
        #pragma unroll
        for (int s = 0; s < 16; ++s){
            const int t = 4*(s&3) + (s>>2);
            X[sB*1024 + t*64 + ((jB + t) & 63)] = pkc(v[s]);
        }
    }
    __syncthreads();   // cross-wave: A' gathers from all chunks

    const float CSCALE = 0.1f / (16384.0f * 16384.0f);
    const float invTN2 = 1.0f / 67108.864f;   // 1/(T*N*N)
    const int lane = tid & 63, wvv = tid >> 6;   // 8 waves

    if (!is_packed){
        // single-pass stats: max, sum, direct expsum
        float lm = 0.f, lsum = 0.f, le = 0.f;
        #pragma unroll
        for (int p = 0; p < 2; ++p){
            const int tp = tid + 512*p;
            const int baseA = L1swz(tp);
            float2 v[16];
            #pragma unroll
            for (int s = 0; s < 16; ++s) v[s] = upkc(X[s*1024 + baseA]);
            twchain16<+1>(v, TWOPI_F * (float)tp / 16384.0f);
            dft16_ip<+1>(v);
            const bool j0 = (tp == 0);
            #pragma unroll
            for (int s = 0; s < 16; ++s){
                const int t = 4*(s&3) + (s>>2);
                float uu = CSCALE * (v[s].x*v[s].x + v[s].y*v[s].y);
                bool inv = (t == 8) && j0;
                if (!inv){
                    lm = fmaxf(lm, uu); lsum += uu;
                    float w0 = (t == 0 && j0) ? 2.f : 1.f;
                    le += w0 * __expf(uu * invTN2);
                }
                if (t == 0 && j0) lsum += uu;
            }
        }
        __syncthreads();  // X reads done; reuse as scratch

        float* scratch = (float*)X;
        float wm = waveReduceMax(lm);
        float wsm = waveReduceSum(lsum);
        float wle = waveReduceSum(le);
        if (lane == 0){ scratch[wvv] = wm; scratch[8+wvv] = wsm; scratch[16+wvv] = wle; }
        __syncthreads();
        if (tid == 0){
            float m_b = scratch[0], sumu = scratch[8], sb2 = scratch[16];
            #pragma unroll
            for (int i = 1; i < 8; ++i){
                m_b = fmaxf(m_b, scratch[i]); sumu += scratch[8+i]; sb2 += scratch[16+i];
            }
            rec[M_WAVE + r] = make_float4(m_b, sumu, sb2, 0.f);
        }
    } else {
        // packed autos: A', store z lag-indexed, one stats pass with partner read
        unsigned zpk[2][16];
        #pragma unroll
        for (int p = 0; p < 2; ++p){
            const int tp = tid + 512*p;
            const int baseA = L1swz(tp);
            float2 v[16];
            #pragma unroll
            for (int s = 0; s < 16; ++s) v[s] = upkc(X[s*1024 + baseA]);
            twchain16<+1>(v, TWOPI_F * (float)tp / 16384.0f);
            dft16_ip<+1>(v);
            #pragma unroll
            for (int s = 0; s < 16; ++s) zpk[p][s] = pkc(v[s]);
        }
        __syncthreads();  // all A' reads of X complete
        #pragma unroll
        for (int p = 0; p < 2; ++p){
            const int tp = tid + 512*p;
            #pragma unroll
            for (int s = 0; s < 16; ++s){
                const int t = 4*(s&3) + (s>>2);
                X[t*1024 + tp] = zpk[p][s];    // lag-indexed bf16 z
            }
        }
        __syncthreads();

        float lma = 0.f, lmb = 0.f, lsa = 0.f, lsb = 0.f, lea = 0.f, leb = 0.f;
        #pragma unroll
        for (int p = 0; p < 2; ++p){
            const int tp = tid + 512*p;
            #pragma unroll
            for (int s = 0; s < 16; ++s){
                const int t = 4*(s&3) + (s>>2);
                if (t < 8) continue;
                if (t == 8 && tp == 0) continue;
                const int n = t*1024 + tp;
                float2 z  = upkc(X[n]);
                float2 zc = upkc(X[FFT_N - n]);
                float ar = 0.5f*(z.x + zc.x), ai = 0.5f*(z.y - zc.y);
                float br = 0.5f*(z.x - zc.x), bi = 0.5f*(z.y + zc.y);
                float ua = CSCALE*(ar*ar + ai*ai);
                float ub = CSCALE*(br*br + bi*bi);
                lma = fmaxf(lma, ua); lsa += ua; lea += __expf(ua * invTN2);
                lmb = fmaxf(lmb, ub); lsb += ub; leb += __expf(ub * invTN2);
            }
        }
        float wma = waveReduceMax(lma), wmb = waveReduceMax(lmb);
        float wsa = waveReduceSum(lsa), wsb = waveReduceSum(lsb);
        float wea = waveReduceSum(lea), web = waveReduceSum(leb);
        if (lane == 0){
            scr2[wvv]=wma; scr2[8+wvv]=wmb; scr2[16+wvv]=wsa;
            scr2[24+wvv]=wsb; scr2[32+wvv]=wea; scr2[40+wvv]=web;
        }
        __syncthreads();
        if (tid == 0){
            float m_a = scr2[0], m_b = scr2[8], s_a = scr2[16], s_b = scr2[24];
            float e_a = scr2[32], e_b = scr2[40];
            #pragma unroll
            for (int i = 1; i < 8; ++i){
                m_a = fmaxf(m_a, scr2[i]);    m_b = fmaxf(m_b, scr2[8+i]);
                s_a += scr2[16+i];            s_b += scr2[24+i];
                e_a += scr2[32+i];            e_b += scr2[40+i];
            }
            const int k = r - 496;
            rec[2*k]   = make_float4(m_a, s_a, e_a, 0.f);
            rec[2*k+1] = make_float4(m_b, s_b, e_b, 0.f);
        }
    }
}

// Merge 528 records -> 7 outputs. rec.z = direct expsum partials; no exp here.
__global__ __launch_bounds__(64) void final_kernel(const float4* __restrict__ rec,
                                                   float* __restrict__ out) {
    const int lane = threadIdx.x;
    float mA = 0.f, mC = 0.f;
    double S = 0.0, sA = 0.0, sC = 0.0;
    for (int r = lane; r < NPAIR; r += 64){
        float4 rv = rec[r];
        S += (double)rv.z;
        if (r < M_WAVE){ mA = fmaxf(mA, rv.x); sA += (double)rv.y; }
        else           { mC = fmaxf(mC, rv.x); sC += (double)rv.y; }
    }
    #pragma unroll
    for (int off = 32; off > 0; off >>= 1){
        mA = fmaxf(mA, __shfl_xor(mA, off, 64));
        mC = fmaxf(mC, __shfl_xor(mC, off, 64));
        S  += __shfl_xor(S,  off, 64);
        sA += __shfl_xor(sA, off, 64);
        sC += __shfl_xor(sC, off, 64);
    }
    if (lane == 0){
        const double invN2 = 1.0/67108864.0;
        const float Mall = fmaxf(mA, mC);
        out[0] = (float)(1e-3 * log(S));
        out[1] = (float)((double)Mall*invN2);
        out[2] = mA;
        out[3] = mC;
        out[4] = (float)((sA + sC)*invN2);
        out[5] = (float)sA;
        out[6] = (float)sC;
    }
}

extern "C" void kernel_launch(void* const* d_in, const int* in_sizes, int n_in,
                              void* d_out, int out_size, void* d_ws, size_t ws_size,
                              hipStream_t stream) {
    (void)in_sizes; (void)n_in; (void)out_size; (void)ws_size;
    const float* x = (const float*)d_in[0];
    float* out = (float*)d_out;

    unsigned* spec = (unsigned*)d_ws;                                   // 2 MiB
    float4* rec = (float4*)((char*)d_ws + (size_t)M_WAVE * FFT_N * 4);  // 8448 B
    unsigned* mid = (unsigned*)((char*)d_ws + (size_t)M_WAVE * FFT_N * 4
                                + (size_t)NPAIR * sizeof(float4));      // 2 MiB

    stageA_kernel<<<128, 256, 0, stream>>>(x, mid);
    bc_kernel<<<128, 256, 0, stream>>>(mid, spec);
    pair_kernel<<<512, 512, 0, stream>>>(spec, rec);
    final_kernel<<<1, 64, 0, stream>>>(rec, out);
}

// Round 18
// 47.874 us; speedup vs baseline: 1.1190x; 1.0003x over previous
//
#include <hip/hip_runtime.h>
#include <math.h>

#define M_WAVE 32
#define NLEN 8192
#define FFT_N 16384
#define NPAIR 528   // rec entries: 32 autos (rec[0..31]) + 496 cross (rec[32..527])

#define TWOPI_F 6.28318530717958647692f

__device__ __forceinline__ float2 cadd(float2 a, float2 b){return make_float2(a.x+b.x, a.y+b.y);}
__device__ __forceinline__ float2 csub(float2 a, float2 b){return make_float2(a.x-b.x, a.y-b.y);}
__device__ __forceinline__ float2 cmul(float2 a, float2 b){return make_float2(a.x*b.x-a.y*b.y, a.x*b.y+a.y*b.x);}
__device__ __forceinline__ float2 mul_i (float2 a){return make_float2(-a.y,  a.x);}
__device__ __forceinline__ float2 mul_mi(float2 a){return make_float2( a.y, -a.x);}

// bf16x2 pack/unpack: one complex float2 <-> one u32 (re=low16, im=high16)
__device__ __forceinline__ unsigned pkc(float2 v){
    unsigned r;
    asm("v_cvt_pk_bf16_f32 %0, %1, %2" : "=v"(r) : "v"(v.x), "v"(v.y));
    return r;
}
__device__ __forceinline__ float2 upkc(unsigned u){
    return make_float2(__uint_as_float(u << 16), __uint_as_float(u & 0xFFFF0000u));
}

__device__ __forceinline__ float2 dpp_xor1(float2 v){
    float2 r;
    r.x = __int_as_float(__builtin_amdgcn_mov_dpp(__float_as_int(v.x), 0xB1, 0xF, 0xF, true));
    r.y = __int_as_float(__builtin_amdgcn_mov_dpp(__float_as_int(v.y), 0xB1, 0xF, 0xF, true));
    return r;
}
__device__ __forceinline__ float2 dpp_xor2(float2 v){
    float2 r;
    r.x = __int_as_float(__builtin_amdgcn_mov_dpp(__float_as_int(v.x), 0x4E, 0xF, 0xF, true));
    r.y = __int_as_float(__builtin_amdgcn_mov_dpp(__float_as_int(v.y), 0x4E, 0xF, 0xF, true));
    return r;
}

__device__ __forceinline__ float waveReduceMax(float v) {
    #pragma unroll
    for (int off = 32; off > 0; off >>= 1) v = fmaxf(v, __shfl_down(v, off, 64));
    return v;
}
__device__ __forceinline__ float waveReduceSum(float v) {
    #pragma unroll
    for (int off = 32; off > 0; off >>= 1) v += __shfl_down(v, off, 64);
    return v;
}

// ---------- classic dft16 (natural order) ----------
template<int SGN>
__device__ __forceinline__ void dft16_tail(float2 w[16], float2 v[16]){
    const float C1 = 0.923879532511286756f;
    const float S1 = 0.382683432365089772f;
    const float R2 = 0.707106781186547524f;
    const float G = (SGN < 0) ? -1.0f : 1.0f;
    w[5]  = cmul(w[5],  make_float2( C1,  G*S1));
    w[6]  = cmul(w[6],  make_float2( R2,  G*R2));
    w[7]  = cmul(w[7],  make_float2( S1,  G*C1));
    w[9]  = cmul(w[9],  make_float2( R2,  G*R2));
    w[10] = (SGN<0) ? mul_mi(w[10]) : mul_i(w[10]);
    w[11] = cmul(w[11], make_float2(-R2,  G*R2));
    w[13] = cmul(w[13], make_float2( S1,  G*C1));
    w[14] = cmul(w[14], make_float2(-R2,  G*R2));
    w[15] = cmul(w[15], make_float2(-C1, -G*S1));
    #pragma unroll
    for (int k0 = 0; k0 < 4; ++k0){
        float2 a = w[k0*4+0], b = w[k0*4+1], c = w[k0*4+2], d = w[k0*4+3];
        float2 t0 = cadd(a,c), t1 = csub(a,c), t2 = cadd(b,d), t3 = csub(b,d);
        float2 j3 = (SGN < 0) ? mul_mi(t3) : mul_i(t3);
        v[k0]    = cadd(t0,t2);
        v[k0+4]  = cadd(t1,j3);
        v[k0+8]  = csub(t0,t2);
        v[k0+12] = csub(t1,j3);
    }
}

template<int SGN>
__device__ __forceinline__ void dft16(float2 v[16]){
    float2 w[16];
    #pragma unroll
    for (int n0 = 0; n0 < 4; ++n0){
        float2 a = v[n0], b = v[n0+4], c = v[n0+8], d = v[n0+12];
        float2 t0 = cadd(a,c), t1 = csub(a,c), t2 = cadd(b,d), t3 = csub(b,d);
        float2 j3 = (SGN < 0) ? mul_mi(t3) : mul_i(t3);
        w[n0]    = cadd(t0,t2);
        w[4+n0]  = cadd(t1,j3);
        w[8+n0]  = csub(t0,t2);
        w[12+n0] = csub(t1,j3);
    }
    dft16_tail<SGN>(w, v);
}

// forward DFT16 with inputs 8..15 == 0 (zero-padded), SGN=-1
__device__ __forceinline__ void dft16_zero8(float2 v[16]){
    float2 w[16];
    #pragma unroll
    for (int n0 = 0; n0 < 4; ++n0){
        float2 a = v[n0], b = v[n0+4];
        w[n0]    = cadd(a,b);
        w[4+n0]  = make_float2(a.x + b.y, a.y - b.x);  // a - i b
        w[8+n0]  = csub(a,b);
        w[12+n0] = make_float2(a.x - b.y, a.y + b.x);  // a + i b
    }
    dft16_tail<-1>(w, v);
}

// ---------- in-place dft16, digit-reversed output: slot s holds y[4*(s&3)+(s>>2)].
template<int SGN>
__device__ __forceinline__ void dft16_ip(float2 v[16]){
    const float C1 = 0.923879532511286756f;
    const float S1 = 0.382683432365089772f;
    const float R2 = 0.707106781186547524f;
    const float G = (SGN < 0) ? -1.0f : 1.0f;
    #pragma unroll
    for (int n1 = 0; n1 < 4; ++n1){
        float2 a = v[n1], b = v[n1+4], c = v[n1+8], d = v[n1+12];
        float2 t0 = cadd(a,c), t1 = csub(a,c), t2 = cadd(b,d), t3 = csub(b,d);
        float2 j3 = (SGN < 0) ? mul_mi(t3) : mul_i(t3);
        v[n1]    = cadd(t0,t2);
        v[n1+4]  = cadd(t1,j3);
        v[n1+8]  = csub(t0,t2);
        v[n1+12] = csub(t1,j3);
    }
    v[5]  = cmul(v[5],  make_float2( C1,  G*S1));
    v[6]  = cmul(v[6],  make_float2( R2,  G*R2));
    v[7]  = cmul(v[7],  make_float2( S1,  G*C1));
    v[9]  = cmul(v[9],  make_float2( R2,  G*R2));
    v[10] = (SGN<0) ? mul_mi(v[10]) : mul_i(v[10]);
    v[11] = cmul(v[11], make_float2(-R2,  G*R2));
    v[13] = cmul(v[13], make_float2( S1,  G*C1));
    v[14] = cmul(v[14], make_float2(-R2,  G*R2));
    v[15] = cmul(v[15], make_float2(-C1, -G*S1));
    #pragma unroll
    for (int kl = 0; kl < 4; ++kl){
        float2 a = v[4*kl], b = v[4*kl+1], c = v[4*kl+2], d = v[4*kl+3];
        float2 t0 = cadd(a,c), t1 = csub(a,c), t2 = cadd(b,d), t3 = csub(b,d);
        float2 j3 = (SGN < 0) ? mul_mi(t3) : mul_i(t3);
        v[4*kl]   = cadd(t0,t2);
        v[4*kl+1] = cadd(t1,j3);
        v[4*kl+2] = csub(t0,t2);
        v[4*kl+3] = csub(t1,j3);
    }
}

template<int SGN>
__device__ __forceinline__ void twchain16(float2 v[16], float theta){
    float th = (SGN < 0) ? -theta : theta;
    float s1,c1; __sincosf(th, &s1, &c1);
    float s4,c4; __sincosf(4.0f*th, &s4, &c4);
    float2 w1 = make_float2(c1,s1), w4 = make_float2(c4,s4);
    float2 lo2 = cmul(w1,w1), lo3 = cmul(lo2,w1);
    float2 hi2 = cmul(w4,w4), hi3 = cmul(hi2,w4);
    float2 lo[4] = {make_float2(1.f,0.f), w1, lo2, lo3};
    float2 hi[4] = {make_float2(1.f,0.f), w4, hi2, hi3};
    #pragma unroll
    for (int s = 1; s < 16; ++s){
        v[s] = cmul(v[s], cmul(hi[s>>2], lo[s&3]));
    }
}

__device__ __forceinline__ int L1swz(int e){
    return (e & ~63) | (((e & 63) + ((e >> 6) & 15)) & 63);
}

// F1 (stage A): 256 blocks = 32 m x 8 col-groups, 128 threads, 1 column/thread.
// Same per-thread math as R17; only the block->(m,group) map changed (full-CU coverage).
__global__ __launch_bounds__(128, 1) void stageA_kernel(const float* __restrict__ x,
                                                        unsigned* __restrict__ mid) {
    const int bx = blockIdx.x, m = bx >> 3, grp = bx & 7;
    const int j = grp*128 + threadIdx.x;      // column 0..1023
    float2 v[16];
    #pragma unroll
    for (int s = 0; s < 8; ++s){
        float ph = TWOPI_F * x[m*NLEN + s*1024 + j];
        float sn,cs; __sincosf(ph,&sn,&cs);
        v[s] = make_float2(cs,sn);
    }
    dft16_zero8(v);
    twchain16<-1>(v, TWOPI_F * (float)j / 16384.0f);
    unsigned* dst = mid + (size_t)m*FFT_N + L1swz(j);
    #pragma unroll
    for (int s = 0; s < 16; ++s) dst[s*1024] = pkc(v[s]);
}

// F2 (stages B+C): 256 blocks = 32 m x 8 chunk-groups, 128 threads (2 waves),
// wave wv = chunk g*2+wv. Per-wave body identical to R17's bc_kernel.
__global__ __launch_bounds__(128, 1) void bc_kernel(const unsigned* __restrict__ mid,
                                                    unsigned* __restrict__ spec) {
    __shared__ float2 X[2048];  // 16 KiB, 2 waves x 1024
    const int bx = blockIdx.x, m = bx >> 3, g = bx & 7;
    const int tid = threadIdx.x;
    const int wv = tid >> 6, jB = tid & 63;
    const int ch = g*2 + wv;
    const unsigned* base = mid + (size_t)m*FFT_N + ch*1024;
    float2 v[16];

    #pragma unroll
    for (int t = 0; t < 16; ++t) v[t] = upkc(base[t*64 + ((jB + t) & 63)]);
    dft16<-1>(v);
    twchain16<-1>(v, TWOPI_F * (float)jB / 1024.0f);
    #pragma unroll
    for (int sp = 0; sp < 16; ++sp) X[wv*1024 + sp*64 + ((jB + 4*sp) & 63)] = v[sp];
    // no barrier: stage C reads only this wave's region

    {
        const int bl = (tid & 63) >> 2, jC = tid & 3;
        #pragma unroll
        for (int a = 0; a < 16; ++a)
            v[a] = X[wv*1024 + bl*64 + ((4*a + jC + 4*bl) & 63)];
        dft16<-1>(v);
        twchain16<-1>(v, TWOPI_F * (float)jC / 64.0f);
        const bool odd1 = (jC & 1) != 0;
        const bool odd2 = (jC & 2) != 0;
        #pragma unroll
        for (int e = 0; e < 16; ++e){
            float2 p = dpp_xor2(v[e]);
            float2 t = odd2 ? csub(p, v[e]) : cadd(v[e], p);
            float2 q = dpp_xor1(t);
            float2 re = odd1 ? csub(q, t) : cadd(t, q);
            float2 ro = odd1 ? cadd(q, mul_i(t)) : cadd(t, mul_mi(q));
            v[e] = odd2 ? ro : re;
        }
        const int u = ((jC & 1) << 1) | (jC >> 1);
        uint4* dst = (uint4*)(spec + (size_t)m*FFT_N + ch*1024 + bl*64 + u*16);
        #pragma unroll
        for (int e = 0; e < 4; ++e)
            dst[e] = make_uint4(pkc(v[4*e]), pkc(v[4*e+1]), pkc(v[4*e+2]), pkc(v[4*e+3]));
    }
}

// Pair kernel: 512 blocks; R11-verified network; computed twiddles (R12);
// single-pass stats with direct exp (no max subtraction; exp args << 1).
__global__ __launch_bounds__(512, 4) void pair_kernel(const unsigned* __restrict__ spec,
                                                      float4* __restrict__ rec) {
    __shared__ unsigned X[FFT_N];  // 64 KiB, bf16x2 per element
    __shared__ float scr2[64];
    const int r = blockIdx.x, tid = threadIdx.x;
    const bool is_packed = (r >= 496);
    int a, b;
    if (is_packed){
        const int k = r - 496; a = 2*k; b = 2*k + 1;
    } else {
        int t = r; a = 0; int rem = M_WAVE - 1;
        while (t >= rem){ t -= rem; ++a; rem = M_WAVE - 1 - a; }
        b = a + 1 + t;
    }
    const int jC = tid & 3;
    const int u = ((jC & 1) << 1) | (jC >> 1);
    const bool odd1 = (jC & 1) != 0;
    const bool odd2 = (jC & 2) != 0;

    // Stage C' (both passes)
    #pragma unroll
    for (int p = 0; p < 2; ++p){
        const int blk = (tid >> 2) + 128*p;   // [0,256)
        float2 v[16];
        const uint4* pa = (const uint4*)(spec + (size_t)a*FFT_N + blk*64 + u*16);
        const uint4* pb = (const uint4*)(spec + (size_t)b*FFT_N + blk*64 + u*16);
        #pragma unroll
        for (int e = 0; e < 4; ++e){
            uint4 A = pa[e], B = pb[e];
            float2 a0 = upkc(A.x), a1 = upkc(A.y), a2 = upkc(A.z), a3 = upkc(A.w);
            float2 b0 = upkc(B.x), b1 = upkc(B.y), b2 = upkc(B.z), b3 = upkc(B.w);
            if (is_packed){
                v[4*e+0] = make_float2(a0.x*a0.x + a0.y*a0.y, b0.x*b0.x + b0.y*b0.y);
                v[4*e+1] = make_float2(a1.x*a1.x + a1.y*a1.y, b1.x*b1.x + b1.y*b1.y);
                v[4*e+2] = make_float2(a2.x*a2.x + a2.y*a2.y, b2.x*b2.x + b2.y*b2.y);
                v[4*e+3] = make_float2(a3.x*a3.x + a3.y*a3.y, b3.x*b3.x + b3.y*b3.y);
            } else {
                v[4*e+0] = make_float2(b0.x*a0.x + b0.y*a0.y, b0.y*a0.x - b0.x*a0.y);
                v[4*e+1] = make_float2(b1.x*a1.x + b1.y*a1.y, b1.y*a1.x - b1.x*a1.y);
                v[4*e+2] = make_float2(b2.x*a2.x + b2.y*a2.y, b2.y*a2.x - b2.x*a2.y);
                v[4*e+3] = make_float2(b3.x*a3.x + b3.y*a3.y, b3.y*a3.x - b3.x*a3.y);
            }
        }
        #pragma unroll
        for (int e = 0; e < 16; ++e){
            float2 q = dpp_xor1(v[e]);
            float2 t = odd1 ? csub(q, v[e]) : cadd(v[e], q);
            float2 pp = dpp_xor2(t);
            float2 re = odd2 ? csub(pp, t) : cadd(t, pp);
            float2 ro = odd2 ? csub(pp, mul_i(t)) : cadd(t, mul_i(pp));
            v[e] = odd1 ? ro : re;
        }
        twchain16<+1>(v, TWOPI_F * (float)jC / 64.0f);
        dft16_ip<+1>(v);
        const int rot = 4*(blk & 15);
        #pragma unroll
        for (int s = 0; s < 16; ++s){
            const int t = 4*(s&3) + (s>>2);   // digit held in slot s
            X[blk*64 + ((4*t + jC + rot) & 63)] = pkc(v[s]);
        }
    }
    // Stage B' (both passes; wave-local)
    const int wv = tid >> 6, jB = tid & 63;
    #pragma unroll
    for (int p = 0; p < 2; ++p){
        const int sB = wv + 8*p;
        float2 v[16];
        #pragma unroll
        for (int sp = 0; sp < 16; ++sp) v[sp] = upkc(X[sB*1024 + sp*64 + ((jB + 4*sp) & 63)]);
        twchain16<+1>(v, TWOPI_F * (float)jB / 1024.0f);
        dft16_ip<+1>(v);
        #pragma unroll
        for (int s = 0; s < 16; ++s){
            const int t = 4*(s&3) + (s>>2);
            X[sB*1024 + t*64 + ((jB + t) & 63)] = pkc(v[s]);
        }
    }
    __syncthreads();   // cross-wave: A' gathers from all chunks

    const float CSCALE = 0.1f / (16384.0f * 16384.0f);
    const float invTN2 = 1.0f / 67108.864f;   // 1/(T*N*N)
    const int lane = tid & 63, wvv = tid >> 6;   // 8 waves

    if (!is_packed){
        // single-pass stats: max, sum, direct expsum
        float lm = 0.f, lsum = 0.f, le = 0.f;
        #pragma unroll
        for (int p = 0; p < 2; ++p){
            const int tp = tid + 512*p;
            const int baseA = L1swz(tp);
            float2 v[16];
            #pragma unroll
            for (int s = 0; s < 16; ++s) v[s] = upkc(X[s*1024 + baseA]);
            twchain16<+1>(v, TWOPI_F * (float)tp / 16384.0f);
            dft16_ip<+1>(v);
            const bool j0 = (tp == 0);
            #pragma unroll
            for (int s = 0; s < 16; ++s){
                const int t = 4*(s&3) + (s>>2);
                float uu = CSCALE * (v[s].x*v[s].x + v[s].y*v[s].y);
                bool inv = (t == 8) && j0;
                if (!inv){
                    lm = fmaxf(lm, uu); lsum += uu;
                    float w0 = (t == 0 && j0) ? 2.f : 1.f;
                    le += w0 * __expf(uu * invTN2);
                }
                if (t == 0 && j0) lsum += uu;
            }
        }
        __syncthreads();  // X reads done; reuse as scratch

        float* scratch = (float*)X;
        float wm = waveReduceMax(lm);
        float wsm = waveReduceSum(lsum);
        float wle = waveReduceSum(le);
        if (lane == 0){ scratch[wvv] = wm; scratch[8+wvv] = wsm; scratch[16+wvv] = wle; }
        __syncthreads();
        if (tid == 0){
            float m_b = scratch[0], sumu = scratch[8], sb2 = scratch[16];
            #pragma unroll
            for (int i = 1; i < 8; ++i){
                m_b = fmaxf(m_b, scratch[i]); sumu += scratch[8+i]; sb2 += scratch[16+i];
            }
            rec[M_WAVE + r] = make_float4(m_b, sumu, sb2, 0.f);
        }
    } else {
        // packed autos: A', store z lag-indexed, one stats pass with partner read
        unsigned zpk[2][16];
        #pragma unroll
        for (int p = 0; p < 2; ++p){
            const int tp = tid + 512*p;
            const int baseA = L1swz(tp);
            float2 v[16];
            #pragma unroll
            for (int s = 0; s < 16; ++s) v[s] = upkc(X[s*1024 + baseA]);
            twchain16<+1>(v, TWOPI_F * (float)tp / 16384.0f);
            dft16_ip<+1>(v);
            #pragma unroll
            for (int s = 0; s < 16; ++s) zpk[p][s] = pkc(v[s]);
        }
        __syncthreads();  // all A' reads of X complete
        #pragma unroll
        for (int p = 0; p < 2; ++p){
            const int tp = tid + 512*p;
            #pragma unroll
            for (int s = 0; s < 16; ++s){
                const int t = 4*(s&3) + (s>>2);
                X[t*1024 + tp] = zpk[p][s];    // lag-indexed bf16 z
            }
        }
        __syncthreads();

        float lma = 0.f, lmb = 0.f, lsa = 0.f, lsb = 0.f, lea = 0.f, leb = 0.f;
        #pragma unroll
        for (int p = 0; p < 2; ++p){
            const int tp = tid + 512*p;
            #pragma unroll
            for (int s = 0; s < 16; ++s){
                const int t = 4*(s&3) + (s>>2);
                if (t < 8) continue;
                if (t == 8 && tp == 0) continue;
                const int n = t*1024 + tp;
                float2 z  = upkc(X[n]);
                float2 zc = upkc(X[FFT_N - n]);
                float ar = 0.5f*(z.x + zc.x), ai = 0.5f*(z.y - zc.y);
                float br = 0.5f*(z.x - zc.x), bi = 0.5f*(z.y + zc.y);
                float ua = CSCALE*(ar*ar + ai*ai);
                float ub = CSCALE*(br*br + bi*bi);
                lma = fmaxf(lma, ua); lsa += ua; lea += __expf(ua * invTN2);
                lmb = fmaxf(lmb, ub); lsb += ub; leb += __expf(ub * invTN2);
            }
        }
        float wma = waveReduceMax(lma), wmb = waveReduceMax(lmb);
        float wsa = waveReduceSum(lsa), wsb = waveReduceSum(lsb);
        float wea = waveReduceSum(lea), web = waveReduceSum(leb);
        if (lane == 0){
            scr2[wvv]=wma; scr2[8+wvv]=wmb; scr2[16+wvv]=wsa;
            scr2[24+wvv]=wsb; scr2[32+wvv]=wea; scr2[40+wvv]=web;
        }
        __syncthreads();
        if (tid == 0){
            float m_a = scr2[0], m_b = scr2[8], s_a = scr2[16], s_b = scr2[24];
            float e_a = scr2[32], e_b = scr2[40];
            #pragma unroll
            for (int i = 1; i < 8; ++i){
                m_a = fmaxf(m_a, scr2[i]);    m_b = fmaxf(m_b, scr2[8+i]);
                s_a += scr2[16+i];            s_b += scr2[24+i];
                e_a += scr2[32+i];            e_b += scr2[40+i];
            }
            const int k = r - 496;
            rec[2*k]   = make_float4(m_a, s_a, e_a, 0.f);
            rec[2*k+1] = make_float4(m_b, s_b, e_b, 0.f);
        }
    }
}

// Merge 528 records -> 7 outputs. rec.z = direct expsum partials; no exp here.
__global__ __launch_bounds__(64) void final_kernel(const float4* __restrict__ rec,
                                                   float* __restrict__ out) {
    const int lane = threadIdx.x;
    float mA = 0.f, mC = 0.f;
    double S = 0.0, sA = 0.0, sC = 0.0;
    for (int r = lane; r < NPAIR; r += 64){
        float4 rv = rec[r];
        S += (double)rv.z;
        if (r < M_WAVE){ mA = fmaxf(mA, rv.x); sA += (double)rv.y; }
        else           { mC = fmaxf(mC, rv.x); sC += (double)rv.y; }
    }
    #pragma unroll
    for (int off = 32; off > 0; off >>= 1){
        mA = fmaxf(mA, __shfl_xor(mA, off, 64));
        mC = fmaxf(mC, __shfl_xor(mC, off, 64));
        S  += __shfl_xor(S,  off, 64);
        sA += __shfl_xor(sA, off, 64);
        sC += __shfl_xor(sC, off, 64);
    }
    if (lane == 0){
        const double invN2 = 1.0/67108864.0;
        const float Mall = fmaxf(mA, mC);
        out[0] = (float)(1e-3 * log(S));
        out[1] = (float)((double)Mall*invN2);
        out[2] = mA;
        out[3] = mC;
        out[4] = (float)((sA + sC)*invN2);
        out[5] = (float)sA;
        out[6] = (float)sC;
    }
}

extern "C" void kernel_launch(void* const* d_in, const int* in_sizes, int n_in,
                              void* d_out, int out_size, void* d_ws, size_t ws_size,
                              hipStream_t stream) {
    (void)in_sizes; (void)n_in; (void)out_size; (void)ws_size;
    const float* x = (const float*)d_in[0];
    float* out = (float*)d_out;

    unsigned* spec = (unsigned*)d_ws;                                   // 2 MiB
    float4* rec = (float4*)((char*)d_ws + (size_t)M_WAVE * FFT_N * 4);  // 8448 B
    unsigned* mid = (unsigned*)((char*)d_ws + (size_t)M_WAVE * FFT_N * 4
                                + (size_t)NPAIR * sizeof(float4));      // 2 MiB

    stageA_kernel<<<256, 128, 0, stream>>>(x, mid);
    bc_kernel<<<256, 128, 0, stream>>>(mid, spec);
    pair_kernel<<<512, 512, 0, stream>>>(spec, rec);
    final_kernel<<<1, 64, 0, stream>>>(rec, out);
}